// Round 20
// baseline (155.510 us; speedup 1.0000x reference)
//
#include <hip/hip_runtime.h>
#include <hip/hip_bf16.h>

typedef __attribute__((ext_vector_type(4)))  float  f32x4;
typedef __attribute__((ext_vector_type(16))) float  f32x16;
typedef __attribute__((ext_vector_type(8)))  short  bf16x8;
typedef __attribute__((ext_vector_type(4)))  int    int32x4;
typedef __attribute__((ext_vector_type(2)))  unsigned int uint32x2;

#define DEVINL static __device__ __forceinline__
#define GAS __attribute__((address_space(1)))
#define LAS __attribute__((address_space(3)))

DEVINL ushort f2bf(float f) {
  unsigned u = __builtin_bit_cast(unsigned, f);
  unsigned r = u + 0x7fffu + ((u >> 16) & 1u);
  return (ushort)(r >> 16);
}

DEVINL unsigned cvtpk(float lo, float hi) {
  unsigned r;
  asm("v_cvt_pk_bf16_f32 %0, %1, %2" : "=v"(r) : "v"(lo), "v"(hi));
  return r;
}

// ONLY safe with genuinely-distinct values in a and b (equal-valued operands
// may be register-coalesced into a self-swap no-op — rounds 7/8 lesson).
DEVINL void plswap(unsigned &a, unsigned &b) {
  asm("v_permlane32_swap_b32 %0, %1" : "+v"(a), "+v"(b));
}

// raw v_exp_f32 (no OCML denormal wrapper; args bounded by defer-max THR=8)
DEVINL float fexp2(float x) { return __builtin_amdgcn_exp2f(x); }

DEVINL float bf2f(short s) {
  return __builtin_bit_cast(float, ((unsigned)(ushort)s) << 16);
}

DEVINL f32x4 mfma16(bf16x8 a, bf16x8 b, f32x4 c) {
  return __builtin_amdgcn_mfma_f32_16x16x32_bf16(a, b, c, 0, 0, 0);
}
DEVINL f32x16 mfma32(bf16x8 a, bf16x8 b, f32x16 c) {
  return __builtin_amdgcn_mfma_f32_32x32x16_bf16(a, b, c, 0, 0, 0);
}

// ------------------------------------------------------------ slim pre-pass
// blocks [0,448): W [K][N] f32 -> W^T [N][K] bf16 (LDS transpose)
// blocks [448,480): mask -> additive f32 bias
__global__ __launch_bounds__(256)
void prep_k(const int* __restrict__ msk, float* __restrict__ mbias,
            const float* __restrict__ Wq, const float* __restrict__ Wk,
            const float* __restrict__ Wv, const float* __restrict__ Wo,
            ushort* __restrict__ WqT, ushort* __restrict__ WkT,
            ushort* __restrict__ WvT, ushort* __restrict__ WoT)
{
  __shared__ ushort Ts[64][72];
  int id = blockIdx.x;
  if (id >= 448) {
    int tid = (id - 448) * 256 + threadIdx.x;
    if (tid < 8192) mbias[tid] = msk[tid] ? 0.f : -1e30f;
    return;
  }
  const float* src; ushort* dst; int Kd, Nd, lid;
  if (id < 128)      { src = Wq; dst = WqT; Kd = 1024; Nd = 512;  lid = id; }
  else if (id < 224) { src = Wk; dst = WkT; Kd = 768;  Nd = 512;  lid = id - 128; }
  else if (id < 320) { src = Wv; dst = WvT; Kd = 768;  Nd = 512;  lid = id - 224; }
  else               { src = Wo; dst = WoT; Kd = 512;  Nd = 1024; lid = id - 320; }
  const int sh = (Nd == 512) ? 3 : 4;
  const int kb = lid >> sh, nb = lid & ((1 << sh) - 1);
  const int k0 = kb * 64, n0 = nb * 64;
  const int t = threadIdx.x;
  const int r = t >> 2, c0 = (t & 3) * 16;

  const float* sp = src + (size_t)(k0 + r) * Nd + n0 + c0;
  f32x4 v0 = *(const f32x4*)(sp);
  f32x4 v1 = *(const f32x4*)(sp + 4);
  f32x4 v2 = *(const f32x4*)(sp + 8);
  f32x4 v3 = *(const f32x4*)(sp + 12);
  #pragma unroll
  for (int e = 0; e < 4; e++) {
    Ts[c0 + e][r]      = f2bf(v0[e]);
    Ts[c0 + 4 + e][r]  = f2bf(v1[e]);
    Ts[c0 + 8 + e][r]  = f2bf(v2[e]);
    Ts[c0 + 12 + e][r] = f2bf(v3[e]);
  }
  __syncthreads();
  const int n = t >> 2, kc = (t & 3) * 16;
  bf16x8 o0 = *(const bf16x8*)&Ts[n][kc];
  bf16x8 o1 = *(const bf16x8*)&Ts[n][kc + 8];
  ushort* dp = dst + (size_t)(n0 + n) * Kd + k0 + kc;
  *(bf16x8*)dp       = o0;
  *(bf16x8*)(dp + 8) = o1;
}

// ------------------------------------------------------------ GEMM
// PHASE 0: fused QKV.  A = x/ctx read as f32, cvt in regs, ds_write pad-40.
//   Depth-2 register pipeline + counted-vmcnt barrier (T4).
// PHASE 1: out-proj with the 4-split softmax reduce FUSED into A-staging:
//   per thread read 4x Opart fragments + 4x Ml, combine (verbatim reduce_k
//   math), ds_write combined bf16 row to the pad-40 A tile.  Loads issue
//   before the MFMA block (latency cover), combine+write after.
template<int PHASE>
__global__ __launch_bounds__(256)
void mm_k(const float* __restrict__ xf, const float* __restrict__ cf,
          const ushort* __restrict__ WqT, const ushort* __restrict__ WkT,
          const ushort* __restrict__ WvT,
          ushort* __restrict__ Qb, ushort* __restrict__ Kb, ushort* __restrict__ VT,
          const ushort* __restrict__ Opart, const float2* __restrict__ Ml,
          const ushort* __restrict__ WoT,
          float* __restrict__ out, const float* __restrict__ bias)
{
  __shared__ ushort As[2][128 * 40];
  __shared__ ushort Bs[2][128 * 32];

  const float* Af = nullptr; const ushort* BT;
  ushort* Cw = nullptr;
  int Kd, mode, m0, n0;
  if (PHASE == 0) {
    int id = blockIdx.x;
    id = (id & 7) * 96 + (id >> 3);              // XCD swizzle (768 % 8 == 0)
    const int which = id >> 8, local = id & 255;
    m0 = (local >> 2) * 128; n0 = (local & 3) * 128;
    if (which == 0)      { Af = xf; BT = WqT; Cw = Qb; Kd = 1024; mode = 1; }
    else if (which == 1) { Af = cf; BT = WkT; Cw = Kb; Kd = 768;  mode = 1; }
    else                 { Af = cf; BT = WvT; Cw = VT; Kd = 768;  mode = 2; }
  } else {
    int id = blockIdx.x;
    id = (id & 7) * 64 + (id >> 3);              // 512 % 8 == 0
    m0 = (id >> 3) * 128; n0 = (id & 7) * 128;
    BT = WoT; Kd = 512; mode = 0;
  }

  const int t = threadIdx.x, lane = t & 63, w = t >> 6;
  const int wr = w >> 1, wc = w & 1;
  const int g = lane >> 4, ql = lane & 15;

  const int arow = t >> 1, akc = (t & 1) * 16;   // A staging coords (both phases)
  const int srowo = 16 * w + (lane >> 2);
  const int sgg = (lane & 3) ^ ((lane >> 3) & 3);

  f32x4 acc[4][4];
  #pragma unroll
  for (int i = 0; i < 4; i++)
    #pragma unroll
    for (int j = 0; j < 4; j++) acc[i][j] = (f32x4){0.f, 0.f, 0.f, 0.f};

  auto stageB = [&](int buf, int k0) {
    #pragma unroll
    for (int i = 0; i < 2; i++) {
      const int row = i * 64 + srowo;
      const ushort* bsrc = BT + (size_t)(n0 + row) * Kd + k0 + sgg * 8;
      __builtin_amdgcn_global_load_lds((const GAS void*)bsrc,
          (LAS void*)&Bs[buf][(i * 64 + 16 * w) * 32], 16, 0, 0);
    }
  };
  auto loadA_f32 = [&](int k0, f32x4 (&d)[4]) {
    const float* ap = Af + (size_t)(m0 + arow) * Kd + k0 + akc;
    d[0] = *(const f32x4*)(ap);
    d[1] = *(const f32x4*)(ap + 4);
    d[2] = *(const f32x4*)(ap + 8);
    d[3] = *(const f32x4*)(ap + 12);
  };
  auto writeA_f32 = [&](int buf, const f32x4 (&v)[4]) {
    union { unsigned u[4]; int32x4 vv; } w1_, w2_;
    w1_.u[0] = cvtpk(v[0][0], v[0][1]); w1_.u[1] = cvtpk(v[0][2], v[0][3]);
    w1_.u[2] = cvtpk(v[1][0], v[1][1]); w1_.u[3] = cvtpk(v[1][2], v[1][3]);
    w2_.u[0] = cvtpk(v[2][0], v[2][1]); w2_.u[1] = cvtpk(v[2][2], v[2][3]);
    w2_.u[2] = cvtpk(v[3][0], v[3][1]); w2_.u[3] = cvtpk(v[3][2], v[3][3]);
    ushort* dst = &As[0][0] + (size_t)buf * 128 * 40 + arow * 40 + akc;
    *(int32x4*)dst       = w1_.vv;
    *(int32x4*)(dst + 8) = w2_.vv;
  };

  // ---- PHASE1 fused-reduce staging: read split partials + Ml for tile tt
  auto loadP1 = [&](int tt, bf16x8 (&ov)[4][2], float2 (&mlv)[4]) {
    const int h = tt >> 1;
    const int dbase = (tt & 1) * 32 + akc;       // akc = (t&1)*16
    const int mrow = m0 + arow;                  // arow = t>>1
    const int b = mrow >> 11, q = mrow & 2047;
    const int bhq = (b * 8 + h) * 2048 + q;
    #pragma unroll
    for (int s = 0; s < 4; s++) {
      const ushort* op = Opart + (size_t)s * 4194304 + (size_t)bhq * 64 + dbase;
      ov[s][0] = *(const bf16x8*)(op);
      ov[s][1] = *(const bf16x8*)(op + 8);
      mlv[s] = Ml[s * 65536 + bhq];
    }
  };
  auto writeP1 = [&](int buf, const bf16x8 (&ov)[4][2], const float2 (&mlv)[4]) {
    float M = fmaxf(fmaxf(mlv[0].x, mlv[1].x), fmaxf(mlv[2].x, mlv[3].x));
    float wgt[4], L = 0.f;
    #pragma unroll
    for (int s = 0; s < 4; s++) { wgt[s] = mlv[s].y * fexp2(mlv[s].x - M); L += wgt[s]; }
    float invL = 1.f / L;
    float a[16];
    #pragma unroll
    for (int e = 0; e < 16; e++) a[e] = 0.f;
    #pragma unroll
    for (int s = 0; s < 4; s++) {
      float ws = wgt[s] * invL;
      #pragma unroll
      for (int e = 0; e < 8; e++) {
        a[e]     += ws * bf2f(ov[s][0][e]);
        a[8 + e] += ws * bf2f(ov[s][1][e]);
      }
    }
    union { unsigned u[4]; int32x4 vv; } w1_, w2_;
    w1_.u[0] = cvtpk(a[0],  a[1]);  w1_.u[1] = cvtpk(a[2],  a[3]);
    w1_.u[2] = cvtpk(a[4],  a[5]);  w1_.u[3] = cvtpk(a[6],  a[7]);
    w2_.u[0] = cvtpk(a[8],  a[9]);  w2_.u[1] = cvtpk(a[10], a[11]);
    w2_.u[2] = cvtpk(a[12], a[13]); w2_.u[3] = cvtpk(a[14], a[15]);
    ushort* dst = &As[0][0] + (size_t)buf * 128 * 40 + arow * 40 + akc;
    *(int32x4*)dst       = w1_.vv;
    *(int32x4*)(dst + 8) = w2_.vv;
  };

  const int sel = (ql >> 1) & 3;
  const int koff = (g ^ sel) * 8;
  const int NK = Kd >> 5;

  auto mfmaBlock = [&](int cur) {
    bf16x8 af[4], bfr[4];
    #pragma unroll
    for (int i = 0; i < 4; i++) {
      af[i]  = *(const bf16x8*)&As[cur][(wr * 64 + i * 16 + ql) * 40 + g * 8];
      bfr[i] = *(const bf16x8*)&Bs[cur][(wc * 64 + i * 16 + ql) * 32 + koff];
    }
    #pragma unroll
    for (int i = 0; i < 4; i++)
      #pragma unroll
      for (int j = 0; j < 4; j++)
        acc[i][j] = mfma16(af[i], bfr[j], acc[i][j]);
  };

  if (PHASE == 0) {
    f32x4 pS0[4], pS1[4];
    loadA_f32(0, pS0);
    writeA_f32(0, pS0);
    stageB(0, 0);
    loadA_f32(32, pS0);            // tile 1 held in regs across the barrier
    __syncthreads();

    auto bodyP0 = [&](int tt, int cur, f32x4 (&consume)[4], f32x4 (&fill)[4]) {
      const bool nb = (tt + 1 < NK);
      const bool nl = (tt + 2 < NK);
      if (nb) stageB(cur ^ 1, (tt + 1) * 32);     // DMAs first (vmcnt order)
      __builtin_amdgcn_sched_barrier(0);
      if (nl) loadA_f32((tt + 2) * 32, fill);     // 4 reg loads after DMAs
      __builtin_amdgcn_sched_barrier(0);
      mfmaBlock(cur);
      if (nb) writeA_f32(cur ^ 1, consume);
      if (nl) asm volatile("s_waitcnt vmcnt(4) lgkmcnt(0)" ::: "memory");
      else    asm volatile("s_waitcnt vmcnt(0) lgkmcnt(0)" ::: "memory");
      __builtin_amdgcn_s_barrier();
      __builtin_amdgcn_sched_barrier(0);
    };
    for (int tt = 0; tt < NK; tt += 2) {
      bodyP0(tt,     0, pS0, pS1);
      bodyP0(tt + 1, 1, pS1, pS0);
    }
  } else {
    bf16x8 ov[4][2]; float2 mlv[4];
    loadP1(0, ov, mlv);
    writeP1(0, ov, mlv);
    stageB(0, 0);
    __syncthreads();
    for (int tt = 0; tt < NK; tt++) {
      const int cur = tt & 1;
      const bool nb = (tt + 1 < NK);
      if (nb) { stageB(cur ^ 1, (tt + 1) * 32); loadP1(tt + 1, ov, mlv); }
      mfmaBlock(cur);
      if (nb) writeP1(cur ^ 1, ov, mlv);
      __syncthreads();
    }
  }

  #pragma unroll
  for (int i = 0; i < 4; i++) {
    #pragma unroll
    for (int j = 0; j < 4; j++) {
      int col = n0 + wc * 64 + j * 16 + ql;
      #pragma unroll
      for (int r = 0; r < 4; r++) {
        int mrow = m0 + wr * 64 + i * 16 + g * 4 + r;
        float v = acc[i][j][r];
        if (PHASE == 1) {
          out[(size_t)mrow * 1024 + col] = v + bias[col];
        } else {
          int b = mrow >> 11, nn = mrow & 2047;
          int hh = col >> 6, dd = col & 63;
          size_t base = (size_t)(b * 8 + hh) * 131072;
          if (mode == 1) Cw[base + (size_t)nn * 64 + dd]   = f2bf(v);
          else           Cw[base + (size_t)dd * 2048 + nn] = f2bf(v);
        }
      }
    }
  }
}

// ------------------------------------------------------------ attention
// (verbatim R17/R19 — K AND V LDS-staged via coalesced DMA, dbuf, XOR swizzle
// on source + read; mask as additive f32 bias; raw v_exp_f32; MFMA row-sum.)
__global__ __launch_bounds__(512)
void attn_k(const ushort* __restrict__ Qb, const ushort* __restrict__ Kb,
            const ushort* __restrict__ VT, const float* __restrict__ mb,
            ushort* __restrict__ Opart, float2* __restrict__ Ml)
{
  constexpr int CHUNK = 512, NT = CHUNK / 64;
  __shared__ ushort Ks[2][64 * 64];
  __shared__ ushort Vs[2][64 * 64];

  const int bh = blockIdx.x, b = bh >> 3;
  const int sp = blockIdx.z;
  const int jb = sp * CHUNK;
  const int t = threadIdx.x, lane = t & 63, w = t >> 6;   // w = 0..7
  const int l31 = lane & 31, hi = lane >> 5;
  const int q0 = blockIdx.y * 256 + w * 32;

  const ushort* Qh = Qb + (size_t)bh * 131072;
  const ushort* Kh = Kb + (size_t)bh * 131072;
  const ushort* Vh = VT + (size_t)bh * 131072;
  const float* mp = mb + b * 2048 + 4 * hi;

  const int srow = lane >> 3;                    // 0..7
  const int soff = ((lane & 7) * 16) ^ ((srow & 7) << 4);

  auto stage = [&](int buf, int j0) {
    const char* kg = (const char*)Kh + ((size_t)(j0 + 8 * w + srow)) * 128 + soff;
    __builtin_amdgcn_global_load_lds((const GAS void*)kg,
        (LAS void*)&Ks[buf][8 * w * 64], 16, 0, 0);
    const char* vg = (const char*)Vh + ((size_t)(8 * w + srow)) * 4096 + (size_t)j0 * 2 + soff;
    __builtin_amdgcn_global_load_lds((const GAS void*)vg,
        (LAS void*)&Vs[buf][8 * w * 64], 16, 0, 0);
  };

  bf16x8 qf[4];
  #pragma unroll
  for (int kk = 0; kk < 4; kk++)
    qf[kk] = *(const bf16x8*)(Qh + (size_t)(q0 + l31) * 64 + kk * 16 + 8 * hi);

  union { unsigned u[4]; bf16x8 v; } ones;
  ones.u[0] = 0x3F803F80u; ones.u[1] = 0x3F803F80u;
  ones.u[2] = 0x3F803F80u; ones.u[3] = 0x3F803F80u;

  f32x16 o0 = {}, o1 = {};
  float m = -1e30f, lsum = 0.f;
  const float sc = 0.18033688011112042f;  // (1/8) * log2(e)

  stage(0, jb);
  __syncthreads();

  for (int tt = 0; tt < NT; ++tt) {
    const int cur = tt & 1;
    if (tt + 1 < NT) stage(cur ^ 1, jb + (tt + 1) * 64);

    #pragma unroll
    for (int js = 0; js < 2; ++js) {
      const int jloc = js * 32;
      const int j0 = jb + tt * 64 + jloc;

      f32x4 mb0 = *(const f32x4*)(mp + j0);
      f32x4 mb1 = *(const f32x4*)(mp + j0 + 8);
      f32x4 mb2 = *(const f32x4*)(mp + j0 + 16);
      f32x4 mb3 = *(const f32x4*)(mp + j0 + 24);

      const int krow = jloc + l31;
      const unsigned rsw = (unsigned)((l31 & 7) << 4);
      const char* kbase = (const char*)&Ks[cur][0] + krow * 128;
      bf16x8 kf0 = *(const bf16x8*)(kbase + ((0  + hi * 16) ^ rsw));
      bf16x8 kf1 = *(const bf16x8*)(kbase + ((32 + hi * 16) ^ rsw));
      bf16x8 kf2 = *(const bf16x8*)(kbase + ((64 + hi * 16) ^ rsw));
      bf16x8 kf3 = *(const bf16x8*)(kbase + ((96 + hi * 16) ^ rsw));

      __builtin_amdgcn_s_setprio(1);
      f32x16 z = {};
      f32x16 s = mfma32(kf0, qf[0], z);
      s = mfma32(kf1, qf[1], s);
      s = mfma32(kf2, qf[2], s);
      s = mfma32(kf3, qf[3], s);
      __builtin_amdgcn_s_setprio(0);

      const char* vb0 = (const char*)&Vs[cur][0] + l31 * 128;
      const char* vb1 = vb0 + 32 * 128;
      const unsigned vc0 = (unsigned)((jloc * 2 + hi * 16) ^ rsw);
      const unsigned vc1 = (unsigned)((jloc * 2 + 32 + hi * 16) ^ rsw);
      bf16x8 vf00 = *(const bf16x8*)(vb0 + vc0);
      bf16x8 vf01 = *(const bf16x8*)(vb0 + vc1);
      bf16x8 vf10 = *(const bf16x8*)(vb1 + vc0);
      bf16x8 vf11 = *(const bf16x8*)(vb1 + vc1);

      float pv[16];
      #pragma unroll
      for (int e = 0; e < 4; e++) {
        pv[e]      = fmaf(s[e],      sc, mb0[e]);
        pv[4 + e]  = fmaf(s[4 + e],  sc, mb1[e]);
        pv[8 + e]  = fmaf(s[8 + e],  sc, mb2[e]);
        pv[12 + e] = fmaf(s[12 + e], sc, mb3[e]);
      }

      float t0 = fmaxf(fmaxf(pv[0],  pv[1]),  pv[2]);
      float t1 = fmaxf(fmaxf(pv[3],  pv[4]),  pv[5]);
      float t2 = fmaxf(fmaxf(pv[6],  pv[7]),  pv[8]);
      float t3 = fmaxf(fmaxf(pv[9],  pv[10]), pv[11]);
      float t4 = fmaxf(fmaxf(pv[12], pv[13]), pv[14]);
      float pm = fmaxf(fmaxf(fmaxf(t0, t1), t2), fmaxf(fmaxf(t3, t4), pv[15]));
      pm = fmaxf(pm, __shfl_xor(pm, 32));

      if (!__all(pm <= m + 8.f)) {
        float mn = fmaxf(m, pm);
        float al = fexp2(m - mn);
        lsum *= al;
        #pragma unroll
        for (int r = 0; r < 16; r++) { o0[r] *= al; o1[r] *= al; }
        m = mn;
      }

      #pragma unroll
      for (int r = 0; r < 16; r++) pv[r] = fexp2(pv[r] - m);

      unsigned pk01 = cvtpk(pv[0],  pv[1]),  pk23 = cvtpk(pv[2],  pv[3]);
      unsigned pk45 = cvtpk(pv[4],  pv[5]),  pk67 = cvtpk(pv[6],  pv[7]);
      unsigned pk89 = cvtpk(pv[8],  pv[9]),  pkAB = cvtpk(pv[10], pv[11]);
      unsigned pkCD = cvtpk(pv[12], pv[13]), pkEF = cvtpk(pv[14], pv[15]);
      plswap(pk01, pk45);
      plswap(pk23, pk67);
      plswap(pk89, pkCD);
      plswap(pkAB, pkEF);
      union { unsigned u[4]; bf16x8 v; } pf0, pf1;
      pf0.u[0] = pk01; pf0.u[1] = pk23; pf0.u[2] = pk45; pf0.u[3] = pk67;
      pf1.u[0] = pk89; pf1.u[1] = pkAB; pf1.u[2] = pkCD; pf1.u[3] = pkEF;

      __builtin_amdgcn_s_setprio(1);
      f32x16 zs = {};
      zs = mfma32(ones.v, pf0.v, zs);
      zs = mfma32(ones.v, pf1.v, zs);
      o0 = mfma32(vf00, pf0.v, o0);
      o0 = mfma32(vf01, pf1.v, o0);
      o1 = mfma32(vf10, pf0.v, o1);
      o1 = mfma32(vf11, pf1.v, o1);
      __builtin_amdgcn_s_setprio(0);
      lsum += zs[0];
    }
    __syncthreads();
  }

  float inv = lsum > 0.f ? 1.0f / lsum : 0.f;
  const int q = q0 + l31;
  ushort* op = Opart + (size_t)sp * 4194304 + ((size_t)(bh * 2048 + q)) * 64;
  #pragma unroll
  for (int grp = 0; grp < 4; grp++) {
    int d0 = grp * 8 + 4 * hi;
    uint32x2 w0, w1;
    w0[0] = cvtpk(o0[4 * grp] * inv, o0[4 * grp + 1] * inv);
    w0[1] = cvtpk(o0[4 * grp + 2] * inv, o0[4 * grp + 3] * inv);
    w1[0] = cvtpk(o1[4 * grp] * inv, o1[4 * grp + 1] * inv);
    w1[1] = cvtpk(o1[4 * grp + 2] * inv, o1[4 * grp + 3] * inv);
    *(uint32x2*)(op + d0)      = w0;
    *(uint32x2*)(op + 32 + d0) = w1;
  }
  if (hi == 0) {
    float2 v; v.x = m; v.y = lsum;
    Ml[sp * 65536 + bh * 2048 + q] = v;
  }
}

extern "C" void kernel_launch(void* const* d_in, const int* in_sizes, int n_in,
                              void* d_out, int out_size, void* d_ws, size_t ws_size,
                              hipStream_t stream)
{
  const float* x   = (const float*)d_in[0];
  const float* ctx = (const float*)d_in[1];
  const int*   mk  = (const int*)d_in[2];
  const float* Wq  = (const float*)d_in[3];
  const float* Wk  = (const float*)d_in[4];
  const float* Wv  = (const float*)d_in[5];
  const float* Wo  = (const float*)d_in[6];
  const float* bo  = (const float*)d_in[7];
  float* out = (float*)d_out;

  // Workspace plan:
  //  [0,8M):   Qb
  //  [8M,16M): Kb
  //  [16M,24M):VT
  //  [24M,25M):WoT [1024][512] bf16
  //  [25M,+32K): mb  float[4][2048]
  //  then: WqT 1M | WkT .75M | WvT .75M | Opart 32M | Ml 2M
  ushort* Qb  = (ushort*)d_ws;
  ushort* Kb  = Qb + 4194304;
  ushort* VT  = Kb + 4194304;
  ushort* WoT = VT + 4194304;
  float*  mb  = (float*)(WoT + 524288);
  ushort* R2  = WoT + 524288 + 16384;
  ushort* WqT = R2;
  ushort* WkT = WqT + 524288;
  ushort* WvT = WkT + 393216;
  ushort* Opart = WvT + 393216;
  float2* Ml    = (float2*)(Opart + 16777216);

  prep_k<<<480, 256, 0, stream>>>(mk, mb, Wq, Wk, Wv, Wo, WqT, WkT, WvT, WoT);
  mm_k<0><<<768, 256, 0, stream>>>(x, ctx, WqT, WkT, WvT, Qb, Kb, VT,
                                   nullptr, nullptr, nullptr, nullptr, nullptr);
  attn_k<<<dim3(32, 8, 4), 512, 0, stream>>>(Qb, Kb, VT, mb, Opart, Ml);
  mm_k<1><<<512, 256, 0, stream>>>(nullptr, nullptr, nullptr, nullptr, nullptr,
                                   nullptr, nullptr, nullptr, Opart, Ml, WoT, out, bo);
}

// Round 21
// 140.869 us; speedup vs baseline: 1.1039x; 1.1039x over previous
//
#include <hip/hip_runtime.h>
#include <hip/hip_bf16.h>

typedef __attribute__((ext_vector_type(4)))  float  f32x4;
typedef __attribute__((ext_vector_type(16))) float  f32x16;
typedef __attribute__((ext_vector_type(8)))  short  bf16x8;
typedef __attribute__((ext_vector_type(4)))  int    int32x4;
typedef __attribute__((ext_vector_type(2)))  unsigned int uint32x2;

#define DEVINL static __device__ __forceinline__
#define GAS __attribute__((address_space(1)))
#define LAS __attribute__((address_space(3)))

DEVINL ushort f2bf(float f) {
  unsigned u = __builtin_bit_cast(unsigned, f);
  unsigned r = u + 0x7fffu + ((u >> 16) & 1u);
  return (ushort)(r >> 16);
}

DEVINL unsigned cvtpk(float lo, float hi) {
  unsigned r;
  asm("v_cvt_pk_bf16_f32 %0, %1, %2" : "=v"(r) : "v"(lo), "v"(hi));
  return r;
}

// ONLY safe with genuinely-distinct values in a and b (equal-valued operands
// may be register-coalesced into a self-swap no-op — rounds 7/8 lesson).
DEVINL void plswap(unsigned &a, unsigned &b) {
  asm("v_permlane32_swap_b32 %0, %1" : "+v"(a), "+v"(b));
}

// raw v_exp_f32 (no OCML denormal wrapper; args bounded by defer-max THR=8)
DEVINL float fexp2(float x) { return __builtin_amdgcn_exp2f(x); }

DEVINL float bf2f(short s) {
  return __builtin_bit_cast(float, ((unsigned)(ushort)s) << 16);
}

DEVINL f32x4 mfma16(bf16x8 a, bf16x8 b, f32x4 c) {
  return __builtin_amdgcn_mfma_f32_16x16x32_bf16(a, b, c, 0, 0, 0);
}
DEVINL f32x16 mfma32(bf16x8 a, bf16x8 b, f32x16 c) {
  return __builtin_amdgcn_mfma_f32_32x32x16_bf16(a, b, c, 0, 0, 0);
}

// ------------------------------------------------------------ slim pre-pass
// blocks [0,448): W [K][N] f32 -> W^T [N][K] bf16 (LDS transpose)
// blocks [448,480): mask -> additive f32 bias
__global__ __launch_bounds__(256)
void prep_k(const int* __restrict__ msk, float* __restrict__ mbias,
            const float* __restrict__ Wq, const float* __restrict__ Wk,
            const float* __restrict__ Wv, const float* __restrict__ Wo,
            ushort* __restrict__ WqT, ushort* __restrict__ WkT,
            ushort* __restrict__ WvT, ushort* __restrict__ WoT)
{
  __shared__ ushort Ts[64][72];
  int id = blockIdx.x;
  if (id >= 448) {
    int tid = (id - 448) * 256 + threadIdx.x;
    if (tid < 8192) mbias[tid] = msk[tid] ? 0.f : -1e30f;
    return;
  }
  const float* src; ushort* dst; int Kd, Nd, lid;
  if (id < 128)      { src = Wq; dst = WqT; Kd = 1024; Nd = 512;  lid = id; }
  else if (id < 224) { src = Wk; dst = WkT; Kd = 768;  Nd = 512;  lid = id - 128; }
  else if (id < 320) { src = Wv; dst = WvT; Kd = 768;  Nd = 512;  lid = id - 224; }
  else               { src = Wo; dst = WoT; Kd = 512;  Nd = 1024; lid = id - 320; }
  const int sh = (Nd == 512) ? 3 : 4;
  const int kb = lid >> sh, nb = lid & ((1 << sh) - 1);
  const int k0 = kb * 64, n0 = nb * 64;
  const int t = threadIdx.x;
  const int r = t >> 2, c0 = (t & 3) * 16;

  const float* sp = src + (size_t)(k0 + r) * Nd + n0 + c0;
  f32x4 v0 = *(const f32x4*)(sp);
  f32x4 v1 = *(const f32x4*)(sp + 4);
  f32x4 v2 = *(const f32x4*)(sp + 8);
  f32x4 v3 = *(const f32x4*)(sp + 12);
  #pragma unroll
  for (int e = 0; e < 4; e++) {
    Ts[c0 + e][r]      = f2bf(v0[e]);
    Ts[c0 + 4 + e][r]  = f2bf(v1[e]);
    Ts[c0 + 8 + e][r]  = f2bf(v2[e]);
    Ts[c0 + 12 + e][r] = f2bf(v3[e]);
  }
  __syncthreads();
  const int n = t >> 2, kc = (t & 3) * 16;
  bf16x8 o0 = *(const bf16x8*)&Ts[n][kc];
  bf16x8 o1 = *(const bf16x8*)&Ts[n][kc + 8];
  ushort* dp = dst + (size_t)(n0 + n) * Kd + k0 + kc;
  *(bf16x8*)dp       = o0;
  *(bf16x8*)(dp + 8) = o1;
}

// ------------------------------------------------------------ GEMM
// PHASE 0: fused QKV.  A = x/ctx read as f32, cvt in regs, ds_write pad-40.
//   Depth-2 register pipeline + counted-vmcnt barrier (T4).
// PHASE 1: out-proj via gload_lds + XOR, plain __syncthreads.
// R20 lesson: keep reduce_k SEPARATE — fusing it into PHASE1 staging turns
// clean streaming traffic into strided in-loop loads and regresses.
template<int PHASE>
__global__ __launch_bounds__(256)
void mm_k(const float* __restrict__ xf, const float* __restrict__ cf,
          const ushort* __restrict__ WqT, const ushort* __restrict__ WkT,
          const ushort* __restrict__ WvT,
          ushort* __restrict__ Qb, ushort* __restrict__ Kb, ushort* __restrict__ VT,
          const ushort* __restrict__ AO, const ushort* __restrict__ WoT,
          float* __restrict__ out, const float* __restrict__ bias)
{
  constexpr int AST = (PHASE == 0) ? 40 : 32;
  __shared__ ushort As[2][128 * AST];
  __shared__ ushort Bs[2][128 * 32];

  const float* Af = nullptr; const ushort* Ab = nullptr; const ushort* BT;
  ushort* Cw = nullptr;
  int Kd, mode, m0, n0;
  if (PHASE == 0) {
    int id = blockIdx.x;
    id = (id & 7) * 96 + (id >> 3);              // XCD swizzle (768 % 8 == 0)
    const int which = id >> 8, local = id & 255;
    m0 = (local >> 2) * 128; n0 = (local & 3) * 128;
    if (which == 0)      { Af = xf; BT = WqT; Cw = Qb; Kd = 1024; mode = 1; }
    else if (which == 1) { Af = cf; BT = WkT; Cw = Kb; Kd = 768;  mode = 1; }
    else                 { Af = cf; BT = WvT; Cw = VT; Kd = 768;  mode = 2; }
  } else {
    int id = blockIdx.x;
    id = (id & 7) * 64 + (id >> 3);              // 512 % 8 == 0
    m0 = (id >> 3) * 128; n0 = (id & 7) * 128;
    Ab = AO; BT = WoT; Kd = 512; mode = 0;
  }

  const int t = threadIdx.x, lane = t & 63, w = t >> 6;
  const int wr = w >> 1, wc = w & 1;
  const int g = lane >> 4, ql = lane & 15;

  const int arow = t >> 1, akc = (t & 1) * 16;   // PHASE0 A staging coords
  const int srowo = 16 * w + (lane >> 2);
  const int sgg = (lane & 3) ^ ((lane >> 3) & 3);

  f32x4 acc[4][4];
  #pragma unroll
  for (int i = 0; i < 4; i++)
    #pragma unroll
    for (int j = 0; j < 4; j++) acc[i][j] = (f32x4){0.f, 0.f, 0.f, 0.f};

  auto stageB = [&](int buf, int k0) {
    #pragma unroll
    for (int i = 0; i < 2; i++) {
      const int row = i * 64 + srowo;
      const ushort* bsrc = BT + (size_t)(n0 + row) * Kd + k0 + sgg * 8;
      __builtin_amdgcn_global_load_lds((const GAS void*)bsrc,
          (LAS void*)&Bs[buf][(i * 64 + 16 * w) * 32], 16, 0, 0);
    }
  };
  auto stageA_lds = [&](int buf, int k0) {       // PHASE1 only
    #pragma unroll
    for (int i = 0; i < 2; i++) {
      const int row = i * 64 + srowo;
      const ushort* asrc = Ab + (size_t)(m0 + row) * Kd + k0 + sgg * 8;
      __builtin_amdgcn_global_load_lds((const GAS void*)asrc,
          (LAS void*)&As[buf][(i * 64 + 16 * w) * 32], 16, 0, 0);
    }
  };
  auto loadA_f32 = [&](int k0, f32x4 (&d)[4]) {
    const float* ap = Af + (size_t)(m0 + arow) * Kd + k0 + akc;
    d[0] = *(const f32x4*)(ap);
    d[1] = *(const f32x4*)(ap + 4);
    d[2] = *(const f32x4*)(ap + 8);
    d[3] = *(const f32x4*)(ap + 12);
  };
  auto writeA_f32 = [&](int buf, const f32x4 (&v)[4]) {
    union { unsigned u[4]; int32x4 vv; } w1_, w2_;
    w1_.u[0] = cvtpk(v[0][0], v[0][1]); w1_.u[1] = cvtpk(v[0][2], v[0][3]);
    w1_.u[2] = cvtpk(v[1][0], v[1][1]); w1_.u[3] = cvtpk(v[1][2], v[1][3]);
    w2_.u[0] = cvtpk(v[2][0], v[2][1]); w2_.u[1] = cvtpk(v[2][2], v[2][3]);
    w2_.u[2] = cvtpk(v[3][0], v[3][1]); w2_.u[3] = cvtpk(v[3][2], v[3][3]);
    ushort* dst = &As[0][0] + (size_t)buf * 128 * 40 + arow * 40 + akc;
    *(int32x4*)dst       = w1_.vv;
    *(int32x4*)(dst + 8) = w2_.vv;
  };

  const int sel = (ql >> 1) & 3;
  const int koff = (g ^ sel) * 8;
  const int NK = Kd >> 5;

  auto mfmaBlock = [&](int cur) {
    bf16x8 af[4], bfr[4];
    #pragma unroll
    for (int i = 0; i < 4; i++) {
      if (PHASE == 0)
        af[i] = *(const bf16x8*)&As[cur][(wr * 64 + i * 16 + ql) * 40 + g * 8];
      else
        af[i] = *(const bf16x8*)&As[cur][(wr * 64 + i * 16 + ql) * 32 + koff];
      bfr[i] = *(const bf16x8*)&Bs[cur][(wc * 64 + i * 16 + ql) * 32 + koff];
    }
    #pragma unroll
    for (int i = 0; i < 4; i++)
      #pragma unroll
      for (int j = 0; j < 4; j++)
        acc[i][j] = mfma16(af[i], bfr[j], acc[i][j]);
  };

  if (PHASE == 0) {
    f32x4 pS0[4], pS1[4];
    loadA_f32(0, pS0);
    writeA_f32(0, pS0);
    stageB(0, 0);
    loadA_f32(32, pS0);            // tile 1 held in regs across the barrier
    __syncthreads();

    auto bodyP0 = [&](int tt, int cur, f32x4 (&consume)[4], f32x4 (&fill)[4]) {
      const bool nb = (tt + 1 < NK);
      const bool nl = (tt + 2 < NK);
      if (nb) stageB(cur ^ 1, (tt + 1) * 32);     // DMAs first (vmcnt order)
      __builtin_amdgcn_sched_barrier(0);
      if (nl) loadA_f32((tt + 2) * 32, fill);     // 4 reg loads after DMAs
      __builtin_amdgcn_sched_barrier(0);
      mfmaBlock(cur);
      if (nb) writeA_f32(cur ^ 1, consume);
      if (nl) asm volatile("s_waitcnt vmcnt(4) lgkmcnt(0)" ::: "memory");
      else    asm volatile("s_waitcnt vmcnt(0) lgkmcnt(0)" ::: "memory");
      __builtin_amdgcn_s_barrier();
      __builtin_amdgcn_sched_barrier(0);
    };
    for (int tt = 0; tt < NK; tt += 2) {
      bodyP0(tt,     0, pS0, pS1);
      bodyP0(tt + 1, 1, pS1, pS0);
    }
  } else {
    stageA_lds(0, 0);
    stageB(0, 0);
    __syncthreads();
    for (int tt = 0; tt < NK; tt++) {
      const int cur = tt & 1;
      if (tt + 1 < NK) { stageA_lds(cur ^ 1, (tt + 1) * 32); stageB(cur ^ 1, (tt + 1) * 32); }
      mfmaBlock(cur);
      __syncthreads();
    }
  }

  #pragma unroll
  for (int i = 0; i < 4; i++) {
    #pragma unroll
    for (int j = 0; j < 4; j++) {
      int col = n0 + wc * 64 + j * 16 + ql;
      #pragma unroll
      for (int r = 0; r < 4; r++) {
        int mrow = m0 + wr * 64 + i * 16 + g * 4 + r;
        float v = acc[i][j][r];
        if (PHASE == 1) {
          out[(size_t)mrow * 1024 + col] = v + bias[col];
        } else {
          int b = mrow >> 11, nn = mrow & 2047;
          int hh = col >> 6, dd = col & 63;
          size_t base = (size_t)(b * 8 + hh) * 131072;
          if (mode == 1) Cw[base + (size_t)nn * 64 + dd]   = f2bf(v);
          else           Cw[base + (size_t)dd * 2048 + nn] = f2bf(v);
        }
      }
    }
  }
}

// ------------------------------------------------------------ attention
// (verbatim R17/R19 — K AND V LDS-staged via coalesced DMA, dbuf, XOR swizzle
// on source + read; mask as additive f32 bias; raw v_exp_f32; MFMA row-sum.)
__global__ __launch_bounds__(512)
void attn_k(const ushort* __restrict__ Qb, const ushort* __restrict__ Kb,
            const ushort* __restrict__ VT, const float* __restrict__ mb,
            ushort* __restrict__ Opart, float2* __restrict__ Ml)
{
  constexpr int CHUNK = 512, NT = CHUNK / 64;
  __shared__ ushort Ks[2][64 * 64];
  __shared__ ushort Vs[2][64 * 64];

  const int bh = blockIdx.x, b = bh >> 3;
  const int sp = blockIdx.z;
  const int jb = sp * CHUNK;
  const int t = threadIdx.x, lane = t & 63, w = t >> 6;   // w = 0..7
  const int l31 = lane & 31, hi = lane >> 5;
  const int q0 = blockIdx.y * 256 + w * 32;

  const ushort* Qh = Qb + (size_t)bh * 131072;
  const ushort* Kh = Kb + (size_t)bh * 131072;
  const ushort* Vh = VT + (size_t)bh * 131072;
  const float* mp = mb + b * 2048 + 4 * hi;

  const int srow = lane >> 3;                    // 0..7
  const int soff = ((lane & 7) * 16) ^ ((srow & 7) << 4);

  auto stage = [&](int buf, int j0) {
    const char* kg = (const char*)Kh + ((size_t)(j0 + 8 * w + srow)) * 128 + soff;
    __builtin_amdgcn_global_load_lds((const GAS void*)kg,
        (LAS void*)&Ks[buf][8 * w * 64], 16, 0, 0);
    const char* vg = (const char*)Vh + ((size_t)(8 * w + srow)) * 4096 + (size_t)j0 * 2 + soff;
    __builtin_amdgcn_global_load_lds((const GAS void*)vg,
        (LAS void*)&Vs[buf][8 * w * 64], 16, 0, 0);
  };

  bf16x8 qf[4];
  #pragma unroll
  for (int kk = 0; kk < 4; kk++)
    qf[kk] = *(const bf16x8*)(Qh + (size_t)(q0 + l31) * 64 + kk * 16 + 8 * hi);

  union { unsigned u[4]; bf16x8 v; } ones;
  ones.u[0] = 0x3F803F80u; ones.u[1] = 0x3F803F80u;
  ones.u[2] = 0x3F803F80u; ones.u[3] = 0x3F803F80u;

  f32x16 o0 = {}, o1 = {};
  float m = -1e30f, lsum = 0.f;
  const float sc = 0.18033688011112042f;  // (1/8) * log2(e)

  stage(0, jb);
  __syncthreads();

  for (int tt = 0; tt < NT; ++tt) {
    const int cur = tt & 1;
    if (tt + 1 < NT) stage(cur ^ 1, jb + (tt + 1) * 64);

    #pragma unroll
    for (int js = 0; js < 2; ++js) {
      const int jloc = js * 32;
      const int j0 = jb + tt * 64 + jloc;

      f32x4 mb0 = *(const f32x4*)(mp + j0);
      f32x4 mb1 = *(const f32x4*)(mp + j0 + 8);
      f32x4 mb2 = *(const f32x4*)(mp + j0 + 16);
      f32x4 mb3 = *(const f32x4*)(mp + j0 + 24);

      const int krow = jloc + l31;
      const unsigned rsw = (unsigned)((l31 & 7) << 4);
      const char* kbase = (const char*)&Ks[cur][0] + krow * 128;
      bf16x8 kf0 = *(const bf16x8*)(kbase + ((0  + hi * 16) ^ rsw));
      bf16x8 kf1 = *(const bf16x8*)(kbase + ((32 + hi * 16) ^ rsw));
      bf16x8 kf2 = *(const bf16x8*)(kbase + ((64 + hi * 16) ^ rsw));
      bf16x8 kf3 = *(const bf16x8*)(kbase + ((96 + hi * 16) ^ rsw));

      __builtin_amdgcn_s_setprio(1);
      f32x16 z = {};
      f32x16 s = mfma32(kf0, qf[0], z);
      s = mfma32(kf1, qf[1], s);
      s = mfma32(kf2, qf[2], s);
      s = mfma32(kf3, qf[3], s);
      __builtin_amdgcn_s_setprio(0);

      const char* vb0 = (const char*)&Vs[cur][0] + l31 * 128;
      const char* vb1 = vb0 + 32 * 128;
      const unsigned vc0 = (unsigned)((jloc * 2 + hi * 16) ^ rsw);
      const unsigned vc1 = (unsigned)((jloc * 2 + 32 + hi * 16) ^ rsw);
      bf16x8 vf00 = *(const bf16x8*)(vb0 + vc0);
      bf16x8 vf01 = *(const bf16x8*)(vb0 + vc1);
      bf16x8 vf10 = *(const bf16x8*)(vb1 + vc0);
      bf16x8 vf11 = *(const bf16x8*)(vb1 + vc1);

      float pv[16];
      #pragma unroll
      for (int e = 0; e < 4; e++) {
        pv[e]      = fmaf(s[e],      sc, mb0[e]);
        pv[4 + e]  = fmaf(s[4 + e],  sc, mb1[e]);
        pv[8 + e]  = fmaf(s[8 + e],  sc, mb2[e]);
        pv[12 + e] = fmaf(s[12 + e], sc, mb3[e]);
      }

      float t0 = fmaxf(fmaxf(pv[0],  pv[1]),  pv[2]);
      float t1 = fmaxf(fmaxf(pv[3],  pv[4]),  pv[5]);
      float t2 = fmaxf(fmaxf(pv[6],  pv[7]),  pv[8]);
      float t3 = fmaxf(fmaxf(pv[9],  pv[10]), pv[11]);
      float t4 = fmaxf(fmaxf(pv[12], pv[13]), pv[14]);
      float pm = fmaxf(fmaxf(fmaxf(t0, t1), t2), fmaxf(fmaxf(t3, t4), pv[15]));
      pm = fmaxf(pm, __shfl_xor(pm, 32));

      if (!__all(pm <= m + 8.f)) {
        float mn = fmaxf(m, pm);
        float al = fexp2(m - mn);
        lsum *= al;
        #pragma unroll
        for (int r = 0; r < 16; r++) { o0[r] *= al; o1[r] *= al; }
        m = mn;
      }

      #pragma unroll
      for (int r = 0; r < 16; r++) pv[r] = fexp2(pv[r] - m);

      unsigned pk01 = cvtpk(pv[0],  pv[1]),  pk23 = cvtpk(pv[2],  pv[3]);
      unsigned pk45 = cvtpk(pv[4],  pv[5]),  pk67 = cvtpk(pv[6],  pv[7]);
      unsigned pk89 = cvtpk(pv[8],  pv[9]),  pkAB = cvtpk(pv[10], pv[11]);
      unsigned pkCD = cvtpk(pv[12], pv[13]), pkEF = cvtpk(pv[14], pv[15]);
      plswap(pk01, pk45);
      plswap(pk23, pk67);
      plswap(pk89, pkCD);
      plswap(pkAB, pkEF);
      union { unsigned u[4]; bf16x8 v; } pf0, pf1;
      pf0.u[0] = pk01; pf0.u[1] = pk23; pf0.u[2] = pk45; pf0.u[3] = pk67;
      pf1.u[0] = pk89; pf1.u[1] = pkAB; pf1.u[2] = pkCD; pf1.u[3] = pkEF;

      __builtin_amdgcn_s_setprio(1);
      f32x16 zs = {};
      zs = mfma32(ones.v, pf0.v, zs);
      zs = mfma32(ones.v, pf1.v, zs);
      o0 = mfma32(vf00, pf0.v, o0);
      o0 = mfma32(vf01, pf1.v, o0);
      o1 = mfma32(vf10, pf0.v, o1);
      o1 = mfma32(vf11, pf1.v, o1);
      __builtin_amdgcn_s_setprio(0);
      lsum += zs[0];
    }
    __syncthreads();
  }

  float inv = lsum > 0.f ? 1.0f / lsum : 0.f;
  const int q = q0 + l31;
  ushort* op = Opart + (size_t)sp * 4194304 + ((size_t)(bh * 2048 + q)) * 64;
  #pragma unroll
  for (int grp = 0; grp < 4; grp++) {
    int d0 = grp * 8 + 4 * hi;
    uint32x2 w0, w1;
    w0[0] = cvtpk(o0[4 * grp] * inv, o0[4 * grp + 1] * inv);
    w0[1] = cvtpk(o0[4 * grp + 2] * inv, o0[4 * grp + 3] * inv);
    w1[0] = cvtpk(o1[4 * grp] * inv, o1[4 * grp + 1] * inv);
    w1[1] = cvtpk(o1[4 * grp + 2] * inv, o1[4 * grp + 3] * inv);
    *(uint32x2*)(op + d0)      = w0;
    *(uint32x2*)(op + 32 + d0) = w1;
  }
  if (hi == 0) {
    float2 v; v.x = m; v.y = lsum;
    Ml[sp * 65536 + bh * 2048 + q] = v;
  }
}

// Combine 4 split partials: AO[b,q,h*64+d] = sum_s w_s * Opart_s[bh,q,d]
__global__ __launch_bounds__(256)
void reduce_k(const ushort* __restrict__ Opart, const float2* __restrict__ Ml,
              ushort* __restrict__ AO)
{
  const int idx = blockIdx.x * 256 + threadIdx.x;   // 524288 total
  const int d8 = idx & 7, q = (idx >> 3) & 2047, bh = idx >> 14;
  const int b = bh >> 3, h = bh & 7;

  float2 ml[4];
  float M = -1e30f;
  #pragma unroll
  for (int s = 0; s < 4; s++) {
    ml[s] = Ml[s * 65536 + bh * 2048 + q];
    M = fmaxf(M, ml[s].x);
  }
  float wgt[4], L = 0.f;
  #pragma unroll
  for (int s = 0; s < 4; s++) {
    wgt[s] = ml[s].y * fexp2(ml[s].x - M);
    L += wgt[s];
  }
  float invL = 1.f / L;

  float acc[8] = {0.f,0.f,0.f,0.f,0.f,0.f,0.f,0.f};
  #pragma unroll
  for (int s = 0; s < 4; s++) {
    bf16x8 v = *(const bf16x8*)(Opart + (size_t)s * 4194304 +
                                ((size_t)(bh * 2048 + q)) * 64 + d8 * 8);
    float ws = wgt[s] * invL;
    #pragma unroll
    for (int e = 0; e < 8; e++) acc[e] += ws * bf2f(v[e]);
  }

  union { unsigned u[4]; int32x4 v; } pk;
  pk.u[0] = cvtpk(acc[0], acc[1]);
  pk.u[1] = cvtpk(acc[2], acc[3]);
  pk.u[2] = cvtpk(acc[4], acc[5]);
  pk.u[3] = cvtpk(acc[6], acc[7]);
  *(int32x4*)(AO + ((size_t)(b * 2048 + q)) * 512 + h * 64 + d8 * 8) = pk.v;
}

extern "C" void kernel_launch(void* const* d_in, const int* in_sizes, int n_in,
                              void* d_out, int out_size, void* d_ws, size_t ws_size,
                              hipStream_t stream)
{
  const float* x   = (const float*)d_in[0];
  const float* ctx = (const float*)d_in[1];
  const int*   mk  = (const int*)d_in[2];
  const float* Wq  = (const float*)d_in[3];
  const float* Wk  = (const float*)d_in[4];
  const float* Wv  = (const float*)d_in[5];
  const float* Wo  = (const float*)d_in[6];
  const float* bo  = (const float*)d_in[7];
  float* out = (float*)d_out;

  // Workspace plan:
  //  [0,8M):   Qb  -- later aliased as AO (reduce_k output)
  //  [8M,16M): Kb
  //  [16M,24M):VT
  //  [24M,25M):WoT [1024][512] bf16
  //  [25M,+32K): mb  float[4][2048]
  //  then: WqT 1M | WkT .75M | WvT .75M | Opart 32M | Ml 2M
  ushort* Qb  = (ushort*)d_ws;
  ushort* Kb  = Qb + 4194304;
  ushort* VT  = Kb + 4194304;
  ushort* WoT = VT + 4194304;
  float*  mb  = (float*)(WoT + 524288);
  ushort* R2  = WoT + 524288 + 16384;
  ushort* WqT = R2;
  ushort* WkT = WqT + 524288;
  ushort* WvT = WkT + 393216;
  ushort* Opart = WvT + 393216;
  float2* Ml    = (float2*)(Opart + 16777216);
  ushort* AO    = Qb;

  prep_k<<<480, 256, 0, stream>>>(mk, mb, Wq, Wk, Wv, Wo, WqT, WkT, WvT, WoT);
  mm_k<0><<<768, 256, 0, stream>>>(x, ctx, WqT, WkT, WvT, Qb, Kb, VT,
                                   nullptr, nullptr, nullptr, nullptr);
  attn_k<<<dim3(32, 8, 4), 512, 0, stream>>>(Qb, Kb, VT, mb, Opart, Ml);
  reduce_k<<<2048, 256, 0, stream>>>(Opart, Ml, AO);
  mm_k<1><<<512, 256, 0, stream>>>(nullptr, nullptr, nullptr, nullptr, nullptr,
                                   nullptr, nullptr, nullptr, AO, WoT, out, bo);
}